// Round 1
// baseline (454.888 us; speedup 1.0000x reference)
//
#include <hip/hip_runtime.h>

// VQ nearest-codeword: out[r] = E[argmin_v (-2 x_r.E_v + ||E_v||^2)]
// Strategy: 3-pass bf16-split MFMA GEMM (hi*hi + hi*lo + lo*hi) with fused
// per-row top-2 (min, 2nd-min) tracking; rows whose top-2 gap < TAU are
// re-resolved exactly in fp64 by a fallback kernel. Output written directly.

typedef float f32x4 __attribute__((ext_vector_type(4)));
typedef short short8 __attribute__((ext_vector_type(8)));

#define TAU 0.02f

__device__ __forceinline__ unsigned short bf16h(float f) {
  unsigned u = __float_as_uint(f);
  return (unsigned short)((u + 0x7fffu + ((u >> 16) & 1u)) >> 16);
}
__device__ __forceinline__ float bf16f(unsigned short h) {
  return __uint_as_float(((unsigned)h) << 16);
}
__device__ __forceinline__ void split4(float4 v, uint2 &hi, uint2 &lo) {
  unsigned short h0 = bf16h(v.x), h1 = bf16h(v.y), h2 = bf16h(v.z), h3 = bf16h(v.w);
  float l0 = v.x - bf16f(h0), l1 = v.y - bf16f(h1);
  float l2 = v.z - bf16f(h2), l3 = v.w - bf16f(h3);
  hi.x = (unsigned)h0 | ((unsigned)h1 << 16);
  hi.y = (unsigned)h2 | ((unsigned)h3 << 16);
  unsigned short g0 = bf16h(l0), g1 = bf16h(l1), g2 = bf16h(l2), g3 = bf16h(l3);
  lo.x = (unsigned)g0 | ((unsigned)g1 << 16);
  lo.y = (unsigned)g2 | ((unsigned)g3 << 16);
}

// ---- prep: e2f[v] (f32) and e2d[v] (f64) = ||E_v||^2, one wave per row ----
__global__ void prep_e2(const float *__restrict__ E, float *__restrict__ e2f,
                        double *__restrict__ e2d) {
  int wid = threadIdx.x >> 6, lane = threadIdx.x & 63;
  int v = blockIdx.x * 4 + wid;
  const float *row = E + (size_t)v * 256;
  float4 f = *(const float4 *)(row + lane * 4);
  double s = (double)f.x * f.x + (double)f.y * f.y + (double)f.z * f.z +
             (double)f.w * f.w;
#pragma unroll
  for (int off = 32; off > 0; off >>= 1) s += __shfl_down(s, off);
  if (lane == 0) { e2f[v] = (float)s; e2d[v] = s; }
}

// ---- main: 128-row blocks, 32 chunks of 128 cols, BK=32, dbuf LDS ----
__global__ __launch_bounds__(512, 2) void vq_main(
    const float *__restrict__ x, const float *__restrict__ E,
    const float *__restrict__ e2f, float *__restrict__ out,
    unsigned *__restrict__ cnt, unsigned *__restrict__ list) {
  extern __shared__ char smem[];
  char *Ab = smem;           // [2][128 rows][128 B: 32 hi bf16 | 32 lo bf16]
  char *Bb = smem + 32768;   // same for E-tile (cols as rows)

  const int tid = threadIdx.x;
  const int wid = tid >> 6;
  const int lane = tid & 63;
  const int l15 = lane & 15;
  const int g = lane >> 4;
  const int wr = wid >> 1;  // 0..3 : 32-row band
  const int wc = wid & 1;   // 0..1 : 64-col band
  const int rowbase = blockIdx.x * 128;

  // fragment read byte-offsets (hi half; lo = ^64)
  int aoffh[2], boffh[4];
#pragma unroll
  for (int mi = 0; mi < 2; ++mi) {
    int r = wr * 32 + mi * 16 + l15;
    aoffh[mi] = (r * 128 + g * 16) ^ ((r & 7) << 4);
  }
#pragma unroll
  for (int ni = 0; ni < 4; ++ni) {
    int c = wc * 64 + ni * 16 + l15;
    boffh[ni] = (c * 128 + g * 16) ^ ((c & 7) << 4);
  }

  // staging: thread t handles (row r0, k-quad kq) and (row r0+64, kq)
  const int r0 = tid >> 3, kq = tid & 7;
  const int wb0 = (r0 * 128 + kq * 8) ^ ((r0 & 7) << 4);
  const float *axp = x + (size_t)(rowbase + r0) * 256 + kq * 4;
  const float *Ebase = E + (size_t)r0 * 256 + kq * 4;

  f32x4 acc[2][4];
#pragma unroll
  for (int mi = 0; mi < 2; ++mi)
#pragma unroll
    for (int ni = 0; ni < 4; ++ni) acc[mi][ni] = (f32x4){0.f, 0.f, 0.f, 0.f};

  float m1[8], m2[8];
  int i1[8];
#pragma unroll
  for (int s = 0; s < 8; ++s) {
    m1[s] = 3.4e38f; m2[s] = 3.4e38f; i1[s] = 0x7fffffff;
  }

  // prologue: stage (chunk 0, ks 0) into buffer 0
  {
    float4 a0 = *(const float4 *)(axp);
    float4 a1 = *(const float4 *)(axp + 64 * 256);
    float4 b0 = *(const float4 *)(Ebase);
    float4 b1 = *(const float4 *)(Ebase + 64 * 256);
    uint2 h, l;
    split4(a0, h, l); *(uint2 *)(Ab + wb0) = h; *(uint2 *)(Ab + (wb0 ^ 64)) = l;
    split4(a1, h, l); *(uint2 *)(Ab + wb0 + 8192) = h; *(uint2 *)(Ab + ((wb0 + 8192) ^ 64)) = l;
    split4(b0, h, l); *(uint2 *)(Bb + wb0) = h; *(uint2 *)(Bb + (wb0 ^ 64)) = l;
    split4(b1, h, l); *(uint2 *)(Bb + wb0 + 8192) = h; *(uint2 *)(Bb + ((wb0 + 8192) ^ 64)) = l;
  }
  __syncthreads();

  for (int chunk = 0; chunk < 32; ++chunk) {
#pragma unroll
    for (int ks = 0; ks < 8; ++ks) {
      const int curA = (ks & 1) * 16384;
      const bool more = !(chunk == 31 && ks == 7);
      float4 a0, a1, b0, b1;
      if (more) {  // issue next-step global loads early
        int nc = (ks == 7) ? chunk + 1 : chunk;
        int nk = (ks == 7) ? 0 : (ks + 1) * 32;
        const float *ap = axp + nk;
        a0 = *(const float4 *)(ap);
        a1 = *(const float4 *)(ap + 64 * 256);
        const float *bp = Ebase + (size_t)nc * 32768 + nk;
        b0 = *(const float4 *)(bp);
        b1 = *(const float4 *)(bp + 64 * 256);
      }
      short8 ah[2], al[2], bh[4], bl[4];
#pragma unroll
      for (int mi = 0; mi < 2; ++mi) {
        ah[mi] = *(const short8 *)(Ab + curA + aoffh[mi]);
        al[mi] = *(const short8 *)(Ab + curA + (aoffh[mi] ^ 64));
      }
#pragma unroll
      for (int ni = 0; ni < 4; ++ni) {
        bh[ni] = *(const short8 *)(Bb + curA + boffh[ni]);
        bl[ni] = *(const short8 *)(Bb + curA + (boffh[ni] ^ 64));
      }
#pragma unroll
      for (int mi = 0; mi < 2; ++mi)
#pragma unroll
        for (int ni = 0; ni < 4; ++ni) {
          acc[mi][ni] = __builtin_amdgcn_mfma_f32_16x16x32_bf16(ah[mi], bh[ni], acc[mi][ni], 0, 0, 0);
          acc[mi][ni] = __builtin_amdgcn_mfma_f32_16x16x32_bf16(ah[mi], bl[ni], acc[mi][ni], 0, 0, 0);
          acc[mi][ni] = __builtin_amdgcn_mfma_f32_16x16x32_bf16(al[mi], bh[ni], acc[mi][ni], 0, 0, 0);
        }
      if (more) {
        const int nxtA = curA ^ 16384;
        uint2 h, l;
        split4(a0, h, l); *(uint2 *)(Ab + nxtA + wb0) = h; *(uint2 *)(Ab + nxtA + (wb0 ^ 64)) = l;
        split4(a1, h, l); *(uint2 *)(Ab + nxtA + wb0 + 8192) = h; *(uint2 *)(Ab + nxtA + ((wb0 + 8192) ^ 64)) = l;
        split4(b0, h, l); *(uint2 *)(Bb + nxtA + wb0) = h; *(uint2 *)(Bb + nxtA + (wb0 ^ 64)) = l;
        split4(b1, h, l); *(uint2 *)(Bb + nxtA + wb0 + 8192) = h; *(uint2 *)(Bb + nxtA + ((wb0 + 8192) ^ 64)) = l;
      }
      __syncthreads();
    }
    // epilogue: dists + top-2 update, reset acc
    const int cb = chunk * 128 + wc * 64;
#pragma unroll
    for (int ni = 0; ni < 4; ++ni) {
      const int col = cb + ni * 16 + l15;
      const float ev = e2f[col];
#pragma unroll
      for (int mi = 0; mi < 2; ++mi) {
#pragma unroll
        for (int r = 0; r < 4; ++r) {
          float d = fmaf(-2.0f, acc[mi][ni][r], ev);
          const int s = mi * 4 + r;
          bool better = (d < m1[s]) || (d == m1[s] && col < i1[s]);
          float old1 = m1[s];
          m1[s] = better ? d : old1;
          i1[s] = better ? col : i1[s];
          float cand2 = better ? old1 : d;
          m2[s] = (cand2 < m2[s]) ? cand2 : m2[s];
          acc[mi][ni][r] = 0.0f;
        }
      }
    }
  }

  // intra-wave merge across the 16 lanes holding the same rows
#pragma unroll
  for (int s = 0; s < 8; ++s) {
#pragma unroll
    for (int off = 1; off < 16; off <<= 1) {
      float om1 = __shfl_xor(m1[s], off);
      float om2 = __shfl_xor(m2[s], off);
      int oi = __shfl_xor(i1[s], off);
      bool take = (om1 < m1[s]) || (om1 == m1[s] && oi < i1[s]);
      float m1w = take ? om1 : m1[s];
      int i1w = take ? oi : i1[s];
      float m1l = take ? m1[s] : om1;
      float m2w = take ? om2 : m2[s];
      m1[s] = m1w; i1[s] = i1w;
      m2[s] = (m1l < m2w) ? m1l : m2w;
    }
  }

  __syncthreads();  // LDS reuse for state exchange
  float *s_m1 = (float *)smem;
  float *s_m2 = (float *)(smem + 512);
  unsigned *s_i1 = (unsigned *)(smem + 1024);
  unsigned *s_idx = (unsigned *)(smem + 1536);
  const int slot = l15;
  if (wc == 1 && slot < 8) {
    int mi = slot >> 2, rg = slot & 3;
    int rl = wr * 32 + mi * 16 + g * 4 + rg;
    s_m1[rl] = m1[slot]; s_m2[rl] = m2[slot]; s_i1[rl] = (unsigned)i1[slot];
  }
  __syncthreads();
  if (wc == 0 && slot < 8) {
    int mi = slot >> 2, rg = slot & 3;
    int rl = wr * 32 + mi * 16 + g * 4 + rg;
    float om1 = s_m1[rl], om2 = s_m2[rl];
    int oi = (int)s_i1[rl];
    bool take = (om1 < m1[slot]) || (om1 == m1[slot] && oi < i1[slot]);
    float m1w = take ? om1 : m1[slot];
    int i1w = take ? oi : i1[slot];
    float m1l = take ? m1[slot] : om1;
    float m2w = take ? om2 : m2[slot];
    float m2n = (m1l < m2w) ? m1l : m2w;
    if (m2n - m1w < TAU) {
      unsigned p = atomicAdd(cnt, 1u);
      list[p] = (unsigned)(rowbase + rl);
    }
    s_idx[rl] = (unsigned)i1w;
  }
  __syncthreads();
  // cooperative gather-write of winning codewords
  for (int id = tid; id < 128 * 64; id += 512) {
    int r = id >> 6, c4 = id & 63;
    unsigned vi = s_idx[r];
    float4 v = *(const float4 *)(E + (size_t)vi * 256 + c4 * 4);
    *(float4 *)(out + (size_t)(rowbase + r) * 256 + c4 * 4) = v;
  }
}

// ---- fallback: exact fp64 re-argmin for near-tie rows ----
__global__ void vq_fallback(const float *__restrict__ x,
                            const float *__restrict__ E,
                            const double *__restrict__ e2d,
                            float *__restrict__ out,
                            const unsigned *__restrict__ cnt,
                            const unsigned *__restrict__ list) {
  __shared__ double sd[256];
  __shared__ int si[256];
  unsigned n = *cnt;
  for (unsigned i = blockIdx.x; i < n; i += gridDim.x) {
    unsigned row = list[i];
    const float *xr = x + (size_t)row * 256;
    double best = 1e300;
    int bi = 0x7fffffff;
    for (int v = threadIdx.x; v < 4096; v += 256) {
      const float *ev = E + (size_t)v * 256;
      double dot = 0.0;
      for (int k = 0; k < 256; ++k) dot += (double)xr[k] * (double)ev[k];
      double d = -2.0 * dot + e2d[v];
      if (d < best || (d == best && v < bi)) { best = d; bi = v; }
    }
    sd[threadIdx.x] = best; si[threadIdx.x] = bi;
    __syncthreads();
    for (int s = 128; s > 0; s >>= 1) {
      if ((int)threadIdx.x < s) {
        double ob = sd[threadIdx.x + s];
        int oi = si[threadIdx.x + s];
        if (ob < sd[threadIdx.x] ||
            (ob == sd[threadIdx.x] && oi < si[threadIdx.x])) {
          sd[threadIdx.x] = ob; si[threadIdx.x] = oi;
        }
      }
      __syncthreads();
    }
    int win = si[0];
    __syncthreads();
    for (int c = threadIdx.x; c < 256; c += 256)
      out[(size_t)row * 256 + c] = E[(size_t)win * 256 + c];
  }
}

extern "C" void kernel_launch(void *const *d_in, const int *in_sizes, int n_in,
                              void *d_out, int out_size, void *d_ws,
                              size_t ws_size, hipStream_t stream) {
  (void)in_sizes; (void)n_in; (void)out_size; (void)ws_size;
  const float *x = (const float *)d_in[0];
  const float *E = (const float *)d_in[1];
  float *out = (float *)d_out;
  char *ws = (char *)d_ws;
  unsigned *cnt = (unsigned *)ws;                       // 4 B (pad to 16)
  float *e2f = (float *)(ws + 16);                      // 16 KiB
  double *e2d = (double *)(ws + 16 + 16384);            // 32 KiB
  unsigned *list = (unsigned *)(ws + 16 + 16384 + 32768);  // 128 KiB

  hipMemsetAsync(cnt, 0, 4, stream);
  prep_e2<<<1024, 256, 0, stream>>>(E, e2f, e2d);
  vq_main<<<256, 512, 65536, stream>>>(x, E, e2f, out, cnt, list);
  vq_fallback<<<256, 256, 0, stream>>>(x, E, e2d, out, cnt, list);
}